// Round 1
// baseline (593.050 us; speedup 1.0000x reference)
//
#include <hip/hip_runtime.h>
#include <hip/hip_bf16.h>

#define S_LEN   2048
#define D_MODEL 768
#define NH      12
#define HD      64
#define NI      6
#define S2      2046
#define BB      2

// ---------------- fp32 NT GEMM: C[M,N] = A[M,K] * W[N,K]^T ----------------
struct GemmArgs { const float* A; const float* W; float* C; };

constexpr int BM = 128, BN = 64, BKK = 16;

__global__ __launch_bounds__(256) void sgemm_nt(GemmArgs g0, GemmArgs g1, GemmArgs g2,
                                                int M, int N, int K) {
    GemmArgs g = (blockIdx.z == 0) ? g0 : ((blockIdx.z == 1) ? g1 : g2);
    const float* __restrict__ A = g.A;
    const float* __restrict__ W = g.W;
    float* __restrict__ C = g.C;

    __shared__ float As[BKK][BM + 4];
    __shared__ float Bs[BKK][BN + 4];

    const int tid = threadIdx.x;
    const int bm = blockIdx.y * BM;
    const int bn = blockIdx.x * BN;
    const int tx = tid & 15;   // col group: tx*4 .. tx*4+3
    const int ty = tid >> 4;   // row group: ty*8 .. ty*8+7

    float acc[8][4] = {};

    for (int k0 = 0; k0 < K; k0 += BKK) {
        // Load A tile (128x16), 2 float4 per thread, store transposed [k][m]
        #pragma unroll
        for (int r = 0; r < 2; ++r) {
            int f = tid + r * 256;
            int row = f >> 2;            // 0..127
            int kc = (f & 3) * 4;        // 0,4,8,12
            float4 av = *(const float4*)&A[(size_t)(bm + row) * K + k0 + kc];
            As[kc + 0][row] = av.x; As[kc + 1][row] = av.y;
            As[kc + 2][row] = av.z; As[kc + 3][row] = av.w;
        }
        // Load W tile (64x16), 1 float4 per thread
        {
            int row = tid >> 2;          // 0..63
            int kc = (tid & 3) * 4;
            float4 bv = *(const float4*)&W[(size_t)(bn + row) * K + k0 + kc];
            Bs[kc + 0][row] = bv.x; Bs[kc + 1][row] = bv.y;
            Bs[kc + 2][row] = bv.z; Bs[kc + 3][row] = bv.w;
        }
        __syncthreads();
        #pragma unroll
        for (int kk = 0; kk < BKK; ++kk) {
            float4 a0 = *(const float4*)&As[kk][ty * 8];
            float4 a1 = *(const float4*)&As[kk][ty * 8 + 4];
            float4 b0 = *(const float4*)&Bs[kk][tx * 4];
            float ar[8] = {a0.x, a0.y, a0.z, a0.w, a1.x, a1.y, a1.z, a1.w};
            float br[4] = {b0.x, b0.y, b0.z, b0.w};
            #pragma unroll
            for (int i = 0; i < 8; ++i)
                #pragma unroll
                for (int j = 0; j < 4; ++j)
                    acc[i][j] = fmaf(ar[i], br[j], acc[i][j]);
        }
        __syncthreads();
    }
    #pragma unroll
    for (int i = 0; i < 8; ++i) {
        int row = bm + ty * 8 + i;
        float4 o = make_float4(acc[i][0], acc[i][1], acc[i][2], acc[i][3]);
        *(float4*)&C[(size_t)row * N + bn + tx * 4] = o;
    }
}

// ---------------- V column sums per (b, channel) ----------------
__global__ __launch_bounds__(256) void vsum_kernel(const float* __restrict__ v,
                                                   float* __restrict__ vsum) {
    const int b = blockIdx.x;
    const int c = blockIdx.y * 256 + threadIdx.x;
    const int s0 = blockIdx.z * 64;
    float a = 0.f;
    for (int s = s0; s < s0 + 64; ++s)
        a += v[((size_t)(b * S_LEN + s)) * D_MODEL + c];
    atomicAdd(&vsum[b * D_MODEL + c], a);
}

// ---------------- sparse rows (pos = 1 .. 2046) ----------------
// softmax over full 2048 cols where only the (deduped) idx cols are nonzero:
// out = (Vsum + sum_U (e^{s_j}-1) v_j) / (2048 - |U| + sum_U e^{s_j})
__global__ __launch_bounds__(768) void sparse_attn(
    const float* __restrict__ q, const float* __restrict__ k, const float* __restrict__ v,
    const float* __restrict__ vsum, const int* __restrict__ idx,
    float* __restrict__ ao) {
    const int i = blockIdx.x;        // 0..2045
    const int b = blockIdx.y;
    const int pos = i + 1;
    const int c = threadIdx.x;       // channel 0..767 (wave == head)

    int id[NI];
    #pragma unroll
    for (int j = 0; j < NI; ++j) id[j] = idx[i * NI + j];
    bool dup[NI];
    #pragma unroll
    for (int j = 0; j < NI; ++j) {
        bool d = false;
        #pragma unroll
        for (int j2 = 0; j2 < NI; ++j2)
            if (j2 < j) d = d || (id[j2] == id[j]);
        dup[j] = d;
    }

    const size_t rowbase = ((size_t)(b * S_LEN + pos)) * D_MODEL;
    const float qv = q[rowbase + c];
    float acc = vsum[b * D_MODEL + c];
    float Z = 0.f;
    int u = 0;
    #pragma unroll
    for (int j = 0; j < NI; ++j) {
        if (dup[j]) continue;                 // uniform branch (idx uniform per block)
        const size_t kb = ((size_t)(b * S_LEN + id[j])) * D_MODEL;
        float p = qv * k[kb + c];
        #pragma unroll
        for (int off = 32; off; off >>= 1) p += __shfl_xor(p, off);
        float e = expf(p * 0.125f);           // 1/sqrt(64)
        Z += e;
        u += 1;
        acc += (e - 1.f) * v[kb + c];
    }
    Z += (float)(S_LEN - u);
    ao[rowbase + c] = acc / Z;
}

// ---------------- global rows (0 and S-1): full attention ----------------
__global__ __launch_bounds__(256) void global_attn(
    const float* __restrict__ q, const float* __restrict__ k, const float* __restrict__ v,
    float* __restrict__ ao) {
    const int row = (blockIdx.x == 0) ? 0 : (S_LEN - 1);
    const int h = blockIdx.y;
    const int b = blockIdx.z;
    const int tid = threadIdx.x;

    __shared__ float qs[HD];
    __shared__ float sc[S_LEN];
    __shared__ float red[8];
    __shared__ float pacc[256];

    if (tid < HD) qs[tid] = q[((size_t)(b * S_LEN + row)) * D_MODEL + h * HD + tid];
    __syncthreads();

    const float4* q4 = (const float4*)qs;
    for (int t = tid; t < S_LEN; t += 256) {
        const float4* kp = (const float4*)&k[((size_t)(b * S_LEN + t)) * D_MODEL + h * HD];
        float acc = 0.f;
        #pragma unroll
        for (int dd = 0; dd < 16; ++dd) {
            float4 kk = kp[dd];
            float4 qq = q4[dd];
            acc += qq.x * kk.x + qq.y * kk.y + qq.z * kk.z + qq.w * kk.w;
        }
        sc[t] = acc * 0.125f;
    }
    __syncthreads();

    // max
    float m = -1e30f;
    for (int t = tid; t < S_LEN; t += 256) m = fmaxf(m, sc[t]);
    #pragma unroll
    for (int off = 32; off; off >>= 1) m = fmaxf(m, __shfl_xor(m, off));
    if ((tid & 63) == 0) red[tid >> 6] = m;
    __syncthreads();
    m = fmaxf(fmaxf(red[0], red[1]), fmaxf(red[2], red[3]));
    __syncthreads();

    // exp + sum
    float zp = 0.f;
    for (int t = tid; t < S_LEN; t += 256) {
        float e = expf(sc[t] - m);
        sc[t] = e;
        zp += e;
    }
    #pragma unroll
    for (int off = 32; off; off >>= 1) zp += __shfl_xor(zp, off);
    if ((tid & 63) == 0) red[4 + (tid >> 6)] = zp;
    __syncthreads();
    const float Z = red[4] + red[5] + red[6] + red[7];

    // PV
    const int d0 = tid & 63;
    const int grp = tid >> 6;
    float acc = 0.f;
    for (int t = grp; t < S_LEN; t += 4)
        acc += sc[t] * v[((size_t)(b * S_LEN + t)) * D_MODEL + h * HD + d0];
    pacc[tid] = acc;
    __syncthreads();
    if (tid < HD) {
        float o = pacc[tid] + pacc[64 + tid] + pacc[128 + tid] + pacc[192 + tid];
        ao[((size_t)(b * S_LEN + row)) * D_MODEL + h * HD + tid] = o / Z;
    }
}

// ---------------- launch ----------------
extern "C" void kernel_launch(void* const* d_in, const int* in_sizes, int n_in,
                              void* d_out, int out_size, void* d_ws, size_t ws_size,
                              hipStream_t stream) {
    const float* Q  = (const float*)d_in[0];
    const float* K  = (const float*)d_in[1];
    const float* V  = (const float*)d_in[2];
    const float* Wq = (const float*)d_in[3];
    const float* Wk = (const float*)d_in[4];
    const float* Wv = (const float*)d_in[5];
    const float* Wo = (const float*)d_in[6];
    const int*  idx = (const int*)d_in[7];
    float* out = (float*)d_out;

    const size_t NTOK = (size_t)BB * S_LEN;          // 4096
    const size_t SZ = NTOK * D_MODEL;                // 3145728 floats
    float* qb = (float*)d_ws;
    float* kb = qb + SZ;
    float* vb = kb + SZ;
    float* ao = vb + SZ;
    float* vs = ao + SZ;                             // BB*D_MODEL floats

    hipMemsetAsync(vs, 0, BB * D_MODEL * sizeof(float), stream);

    {
        GemmArgs g0{Q, Wq, qb}, g1{K, Wk, kb}, g2{V, Wv, vb};
        dim3 grid(D_MODEL / BN, (int)(NTOK / BM), 3);
        sgemm_nt<<<grid, 256, 0, stream>>>(g0, g1, g2, (int)NTOK, D_MODEL, D_MODEL);
    }
    vsum_kernel<<<dim3(BB, D_MODEL / 256, 32), 256, 0, stream>>>(vb, vs);
    sparse_attn<<<dim3(S2, BB), 768, 0, stream>>>(qb, kb, vb, vs, idx, ao);
    global_attn<<<dim3(2, NH, BB), 256, 0, stream>>>(qb, kb, vb, ao);
    {
        GemmArgs g{ao, Wo, out};
        dim3 grid(D_MODEL / BN, (int)(NTOK / BM), 1);
        sgemm_nt<<<grid, 256, 0, stream>>>(g, g, g, (int)NTOK, D_MODEL, D_MODEL);
    }
}

// Round 2
// 425.115 us; speedup vs baseline: 1.3950x; 1.3950x over previous
//
#include <hip/hip_runtime.h>
#include <hip/hip_bf16.h>

#define S_LEN   2048
#define D_MODEL 768
#define NH      12
#define HD      64
#define NI      6
#define S2      2046
#define BB      2

typedef __attribute__((ext_vector_type(8))) short short8v;   // 8 bf16 (4 VGPR) MFMA A/B frag
typedef __attribute__((ext_vector_type(4))) short short4v;   // 4 bf16, 8B LDS store
typedef __attribute__((ext_vector_type(4))) float f32x4;     // MFMA C/D frag

__device__ __forceinline__ unsigned short bf16_rne(float x) {
    union { float f; unsigned int u; } c; c.f = x;
    unsigned int u = c.u + 0x7fffu + ((c.u >> 16) & 1u);
    return (unsigned short)(u >> 16);
}
__device__ __forceinline__ float bf16_f(unsigned short h) {
    union { unsigned int u; float f; } c; c.u = ((unsigned int)h) << 16;
    return c.f;
}

// ---------------- bf16-split MFMA NT GEMM: C[M,N] = A[M,K] * W[N,K]^T -------
// A = A_hi + A_lo (bf16 each); C = Ah*Bh + Ah*Bl + Al*Bh  (near-fp32 accuracy)
struct GemmArgs { const float* A; const float* W; float* C; };

constexpr int GBM = 128, GBN = 128, GBK = 32;
constexpr int LDK = 40;   // padded row: 80B stride -> 2-way LDS aliasing (free)

__global__ __launch_bounds__(256) void mfma_gemm_nt(GemmArgs g0, GemmArgs g1, GemmArgs g2,
                                                    int N, int K) {
    GemmArgs g = (blockIdx.z == 0) ? g0 : ((blockIdx.z == 1) ? g1 : g2);
    const float* __restrict__ A = g.A;
    const float* __restrict__ W = g.W;
    float* __restrict__ C = g.C;

    __shared__ short Ah[GBM][LDK];
    __shared__ short Al[GBM][LDK];
    __shared__ short Bh[GBM][LDK];
    __shared__ short Bl[GBM][LDK];

    const int tid  = threadIdx.x;
    const int lane = tid & 63;
    const int w    = tid >> 6;
    const int wm   = w & 1;          // wave row  (2x2 wave grid, 64x64 out each)
    const int wn   = w >> 1;         // wave col
    const int bm   = blockIdx.y * GBM;
    const int bn   = blockIdx.x * GBN;

    f32x4 acc[4][4];
    #pragma unroll
    for (int i = 0; i < 4; ++i)
        #pragma unroll
        for (int j = 0; j < 4; ++j)
            acc[i][j] = (f32x4){0.f, 0.f, 0.f, 0.f};

    const int lrow = tid >> 3;         // 0..31
    const int lcol = (tid & 7) * 4;    // 0,4,..,28

    const int fr = lane & 15;          // frag row/col within 16
    const int fk = (lane >> 4) * 8;    // frag k offset

    for (int k0 = 0; k0 < K; k0 += GBK) {
        #pragma unroll
        for (int r = 0; r < 4; ++r) {
            const int row = lrow + r * 32;
            float4 av = *(const float4*)&A[(size_t)(bm + row) * K + k0 + lcol];
            float4 bv = *(const float4*)&W[(size_t)(bn + row) * K + k0 + lcol];
            short4v h4, l4;
            {
                unsigned short h;
                h = bf16_rne(av.x); h4.x = (short)h; l4.x = (short)bf16_rne(av.x - bf16_f(h));
                h = bf16_rne(av.y); h4.y = (short)h; l4.y = (short)bf16_rne(av.y - bf16_f(h));
                h = bf16_rne(av.z); h4.z = (short)h; l4.z = (short)bf16_rne(av.z - bf16_f(h));
                h = bf16_rne(av.w); h4.w = (short)h; l4.w = (short)bf16_rne(av.w - bf16_f(h));
            }
            *(short4v*)&Ah[row][lcol] = h4;
            *(short4v*)&Al[row][lcol] = l4;
            {
                unsigned short h;
                h = bf16_rne(bv.x); h4.x = (short)h; l4.x = (short)bf16_rne(bv.x - bf16_f(h));
                h = bf16_rne(bv.y); h4.y = (short)h; l4.y = (short)bf16_rne(bv.y - bf16_f(h));
                h = bf16_rne(bv.z); h4.z = (short)h; l4.z = (short)bf16_rne(bv.z - bf16_f(h));
                h = bf16_rne(bv.w); h4.w = (short)h; l4.w = (short)bf16_rne(bv.w - bf16_f(h));
            }
            *(short4v*)&Bh[row][lcol] = h4;
            *(short4v*)&Bl[row][lcol] = l4;
        }
        __syncthreads();

        short8v ah[4], al_[4], bh[4], bl_[4];
        #pragma unroll
        for (int i = 0; i < 4; ++i) {
            ah[i]  = *(const short8v*)&Ah[wm * 64 + i * 16 + fr][fk];
            al_[i] = *(const short8v*)&Al[wm * 64 + i * 16 + fr][fk];
            bh[i]  = *(const short8v*)&Bh[wn * 64 + i * 16 + fr][fk];
            bl_[i] = *(const short8v*)&Bl[wn * 64 + i * 16 + fr][fk];
        }
        #pragma unroll
        for (int i = 0; i < 4; ++i)
            #pragma unroll
            for (int j = 0; j < 4; ++j) {
                acc[i][j] = __builtin_amdgcn_mfma_f32_16x16x32_bf16(ah[i],  bh[j],  acc[i][j], 0, 0, 0);
                acc[i][j] = __builtin_amdgcn_mfma_f32_16x16x32_bf16(ah[i],  bl_[j], acc[i][j], 0, 0, 0);
                acc[i][j] = __builtin_amdgcn_mfma_f32_16x16x32_bf16(al_[i], bh[j],  acc[i][j], 0, 0, 0);
            }
        __syncthreads();
    }

    // epilogue: D frag (i,j) reg r -> row = wm*64+i*16+(lane>>4)*4+r, col = wn*64+j*16+(lane&15)
    const int crow0 = bm + wm * 64 + ((lane >> 4) << 2);
    const int ccol0 = bn + wn * 64 + (lane & 15);
    #pragma unroll
    for (int i = 0; i < 4; ++i)
        #pragma unroll
        for (int j = 0; j < 4; ++j)
            #pragma unroll
            for (int r = 0; r < 4; ++r)
                C[(size_t)(crow0 + i * 16 + r) * N + ccol0 + j * 16] = acc[i][j][r];
}

// ---------------- V column sums per (b, channel) ----------------
__global__ __launch_bounds__(256) void vsum_kernel(const float* __restrict__ v,
                                                   float* __restrict__ vsum) {
    const int b = blockIdx.x;
    const int c = blockIdx.y * 256 + threadIdx.x;
    const int s0 = blockIdx.z * 64;
    float a = 0.f;
    for (int s = s0; s < s0 + 64; ++s)
        a += v[((size_t)(b * S_LEN + s)) * D_MODEL + c];
    atomicAdd(&vsum[b * D_MODEL + c], a);
}

// ---------------- sparse rows (pos = 1 .. 2046) ----------------
// softmax over 2048 cols where only (deduped) idx cols are nonzero:
// out = (Vsum + sum_U (e^{s_j}-1) v_j) / (2048 - |U| + sum_U e^{s_j})
__global__ __launch_bounds__(768) void sparse_attn(
    const float* __restrict__ q, const float* __restrict__ k, const float* __restrict__ v,
    const float* __restrict__ vsum, const int* __restrict__ idx,
    float* __restrict__ ao) {
    const int i = blockIdx.x;        // 0..2045
    const int b = blockIdx.y;
    const int pos = i + 1;
    const int c = threadIdx.x;       // channel 0..767 (wave == head)

    int id[NI];
    #pragma unroll
    for (int j = 0; j < NI; ++j) id[j] = idx[i * NI + j];
    bool dup[NI];
    #pragma unroll
    for (int j = 0; j < NI; ++j) {
        bool d = false;
        #pragma unroll
        for (int j2 = 0; j2 < NI; ++j2)
            if (j2 < j) d = d || (id[j2] == id[j]);
        dup[j] = d;
    }

    const size_t rowbase = ((size_t)(b * S_LEN + pos)) * D_MODEL;
    const float qv = q[rowbase + c];

    // issue ALL 12 gathers up front -> independent, in flight together
    float kv[NI], vv[NI];
    #pragma unroll
    for (int j = 0; j < NI; ++j) {
        const size_t kb = ((size_t)(b * S_LEN + id[j])) * D_MODEL + c;
        kv[j] = k[kb];
        vv[j] = v[kb];
    }

    float p[NI];
    #pragma unroll
    for (int j = 0; j < NI; ++j) p[j] = qv * kv[j];

    // interleaved reduction trees (ILP across j)
    #pragma unroll
    for (int off = 32; off; off >>= 1) {
        #pragma unroll
        for (int j = 0; j < NI; ++j) p[j] += __shfl_xor(p[j], off);
    }

    float acc = vsum[b * D_MODEL + c];
    float Z = 0.f;
    int u = 0;
    #pragma unroll
    for (int j = 0; j < NI; ++j) {
        if (dup[j]) continue;                 // uniform branch (idx uniform per block)
        float e = expf(p[j] * 0.125f);        // 1/sqrt(64)
        Z += e;
        u += 1;
        acc += (e - 1.f) * vv[j];
    }
    Z += (float)(S_LEN - u);
    ao[rowbase + c] = acc / Z;
}

// ---------------- global rows (0 and S-1): full attention ----------------
__global__ __launch_bounds__(256) void global_attn(
    const float* __restrict__ q, const float* __restrict__ k, const float* __restrict__ v,
    float* __restrict__ ao) {
    const int row = (blockIdx.x == 0) ? 0 : (S_LEN - 1);
    const int h = blockIdx.y;
    const int b = blockIdx.z;
    const int tid = threadIdx.x;

    __shared__ float qs[HD];
    __shared__ float sc[S_LEN];
    __shared__ float red[8];
    __shared__ float pacc[256];

    if (tid < HD) qs[tid] = q[((size_t)(b * S_LEN + row)) * D_MODEL + h * HD + tid];
    __syncthreads();

    const float4* q4 = (const float4*)qs;
    for (int t = tid; t < S_LEN; t += 256) {
        const float4* kp = (const float4*)&k[((size_t)(b * S_LEN + t)) * D_MODEL + h * HD];
        float acc = 0.f;
        #pragma unroll
        for (int dd = 0; dd < 16; ++dd) {
            float4 kk = kp[dd];
            float4 qq = q4[dd];
            acc += qq.x * kk.x + qq.y * kk.y + qq.z * kk.z + qq.w * kk.w;
        }
        sc[t] = acc * 0.125f;
    }
    __syncthreads();

    float m = -1e30f;
    for (int t = tid; t < S_LEN; t += 256) m = fmaxf(m, sc[t]);
    #pragma unroll
    for (int off = 32; off; off >>= 1) m = fmaxf(m, __shfl_xor(m, off));
    if ((tid & 63) == 0) red[tid >> 6] = m;
    __syncthreads();
    m = fmaxf(fmaxf(red[0], red[1]), fmaxf(red[2], red[3]));
    __syncthreads();

    float zp = 0.f;
    for (int t = tid; t < S_LEN; t += 256) {
        float e = expf(sc[t] - m);
        sc[t] = e;
        zp += e;
    }
    #pragma unroll
    for (int off = 32; off; off >>= 1) zp += __shfl_xor(zp, off);
    if ((tid & 63) == 0) red[4 + (tid >> 6)] = zp;
    __syncthreads();
    const float Z = red[4] + red[5] + red[6] + red[7];

    const int d0 = tid & 63;
    const int grp = tid >> 6;
    float acc = 0.f;
    for (int t = grp; t < S_LEN; t += 4)
        acc += sc[t] * v[((size_t)(b * S_LEN + t)) * D_MODEL + h * HD + d0];
    pacc[tid] = acc;
    __syncthreads();
    if (tid < HD) {
        float o = pacc[tid] + pacc[64 + tid] + pacc[128 + tid] + pacc[192 + tid];
        ao[((size_t)(b * S_LEN + row)) * D_MODEL + h * HD + tid] = o / Z;
    }
}

// ---------------- launch ----------------
extern "C" void kernel_launch(void* const* d_in, const int* in_sizes, int n_in,
                              void* d_out, int out_size, void* d_ws, size_t ws_size,
                              hipStream_t stream) {
    const float* Q  = (const float*)d_in[0];
    const float* K  = (const float*)d_in[1];
    const float* V  = (const float*)d_in[2];
    const float* Wq = (const float*)d_in[3];
    const float* Wk = (const float*)d_in[4];
    const float* Wv = (const float*)d_in[5];
    const float* Wo = (const float*)d_in[6];
    const int*  idx = (const int*)d_in[7];
    float* out = (float*)d_out;

    const size_t NTOK = (size_t)BB * S_LEN;          // 4096
    const size_t SZ = NTOK * D_MODEL;                // 3145728 floats
    float* qb = (float*)d_ws;
    float* kb = qb + SZ;
    float* vb = kb + SZ;
    float* ao = vb + SZ;
    float* vs = ao + SZ;                             // BB*D_MODEL floats

    hipMemsetAsync(vs, 0, BB * D_MODEL * sizeof(float), stream);

    {
        GemmArgs g0{Q, Wq, qb}, g1{K, Wk, kb}, g2{V, Wv, vb};
        dim3 grid(D_MODEL / GBN, (int)(NTOK / GBM), 3);
        mfma_gemm_nt<<<grid, 256, 0, stream>>>(g0, g1, g2, D_MODEL, D_MODEL);
    }
    vsum_kernel<<<dim3(BB, D_MODEL / 256, 32), 256, 0, stream>>>(vb, vs);
    sparse_attn<<<dim3(S2, BB), 768, 0, stream>>>(qb, kb, vb, vs, idx, ao);
    global_attn<<<dim3(2, NH, BB), 256, 0, stream>>>(qb, kb, vb, ao);
    {
        GemmArgs g{ao, Wo, out};
        dim3 grid(D_MODEL / GBN, (int)(NTOK / GBM), 1);
        mfma_gemm_nt<<<grid, 256, 0, stream>>>(g, g, g, D_MODEL, D_MODEL);
    }
}

// Round 3
// 296.254 us; speedup vs baseline: 2.0018x; 1.4350x over previous
//
#include <hip/hip_runtime.h>
#include <hip/hip_bf16.h>

#define S_LEN   2048
#define D_MODEL 768
#define NH      12
#define HD      64
#define NI      6
#define S2      2046
#define BB      2
#define NCH     8
#define CHK     256   // keys per chunk (NCH*CHK == S_LEN)

typedef __attribute__((ext_vector_type(8))) short short8v;   // 8 bf16 (4 VGPR) MFMA A/B frag
typedef __attribute__((ext_vector_type(4))) short short4v;   // 4 bf16, 8B LDS store
typedef __attribute__((ext_vector_type(4))) float f32x4;     // MFMA C/D frag

__device__ __forceinline__ unsigned short bf16_rne(float x) {
    union { float f; unsigned int u; } c; c.f = x;
    unsigned int u = c.u + 0x7fffu + ((c.u >> 16) & 1u);
    return (unsigned short)(u >> 16);
}
__device__ __forceinline__ float bf16_f(unsigned short h) {
    union { unsigned int u; float f; } c; c.u = ((unsigned int)h) << 16;
    return c.f;
}

// ---------------- bf16-split MFMA NT GEMM: C[M,N] = A[M,K] * W[N,K]^T -------
// A = A_hi + A_lo (bf16 each); C = Ah*Bh + Ah*Bl + Al*Bh  (near-fp32 accuracy)
struct GemmArgs { const float* A; const float* W; float* C; };

constexpr int GBM = 128, GBN = 128, GBK = 32;
constexpr int LDK = 40;   // padded row: 80B stride -> 2-way LDS aliasing (free)

__global__ __launch_bounds__(256) void mfma_gemm_nt(GemmArgs g0, GemmArgs g1, GemmArgs g2,
                                                    int N, int K) {
    GemmArgs g = (blockIdx.z == 0) ? g0 : ((blockIdx.z == 1) ? g1 : g2);
    const float* __restrict__ A = g.A;
    const float* __restrict__ W = g.W;
    float* __restrict__ C = g.C;

    __shared__ short Ah[GBM][LDK];
    __shared__ short Al[GBM][LDK];
    __shared__ short Bh[GBM][LDK];
    __shared__ short Bl[GBM][LDK];

    const int tid  = threadIdx.x;
    const int lane = tid & 63;
    const int w    = tid >> 6;
    const int wm   = w & 1;          // wave row  (2x2 wave grid, 64x64 out each)
    const int wn   = w >> 1;         // wave col
    const int bm   = blockIdx.y * GBM;
    const int bn   = blockIdx.x * GBN;

    f32x4 acc[4][4];
    #pragma unroll
    for (int i = 0; i < 4; ++i)
        #pragma unroll
        for (int j = 0; j < 4; ++j)
            acc[i][j] = (f32x4){0.f, 0.f, 0.f, 0.f};

    const int lrow = tid >> 3;         // 0..31
    const int lcol = (tid & 7) * 4;    // 0,4,..,28

    const int fr = lane & 15;          // frag row/col within 16
    const int fk = (lane >> 4) * 8;    // frag k offset

    for (int k0 = 0; k0 < K; k0 += GBK) {
        #pragma unroll
        for (int r = 0; r < 4; ++r) {
            const int row = lrow + r * 32;
            float4 av = *(const float4*)&A[(size_t)(bm + row) * K + k0 + lcol];
            float4 bv = *(const float4*)&W[(size_t)(bn + row) * K + k0 + lcol];
            short4v h4, l4;
            {
                unsigned short h;
                h = bf16_rne(av.x); h4.x = (short)h; l4.x = (short)bf16_rne(av.x - bf16_f(h));
                h = bf16_rne(av.y); h4.y = (short)h; l4.y = (short)bf16_rne(av.y - bf16_f(h));
                h = bf16_rne(av.z); h4.z = (short)h; l4.z = (short)bf16_rne(av.z - bf16_f(h));
                h = bf16_rne(av.w); h4.w = (short)h; l4.w = (short)bf16_rne(av.w - bf16_f(h));
            }
            *(short4v*)&Ah[row][lcol] = h4;
            *(short4v*)&Al[row][lcol] = l4;
            {
                unsigned short h;
                h = bf16_rne(bv.x); h4.x = (short)h; l4.x = (short)bf16_rne(bv.x - bf16_f(h));
                h = bf16_rne(bv.y); h4.y = (short)h; l4.y = (short)bf16_rne(bv.y - bf16_f(h));
                h = bf16_rne(bv.z); h4.z = (short)h; l4.z = (short)bf16_rne(bv.z - bf16_f(h));
                h = bf16_rne(bv.w); h4.w = (short)h; l4.w = (short)bf16_rne(bv.w - bf16_f(h));
            }
            *(short4v*)&Bh[row][lcol] = h4;
            *(short4v*)&Bl[row][lcol] = l4;
        }
        __syncthreads();

        short8v ah[4], al_[4], bh[4], bl_[4];
        #pragma unroll
        for (int i = 0; i < 4; ++i) {
            ah[i]  = *(const short8v*)&Ah[wm * 64 + i * 16 + fr][fk];
            al_[i] = *(const short8v*)&Al[wm * 64 + i * 16 + fr][fk];
            bh[i]  = *(const short8v*)&Bh[wn * 64 + i * 16 + fr][fk];
            bl_[i] = *(const short8v*)&Bl[wn * 64 + i * 16 + fr][fk];
        }
        #pragma unroll
        for (int i = 0; i < 4; ++i)
            #pragma unroll
            for (int j = 0; j < 4; ++j) {
                acc[i][j] = __builtin_amdgcn_mfma_f32_16x16x32_bf16(ah[i],  bh[j],  acc[i][j], 0, 0, 0);
                acc[i][j] = __builtin_amdgcn_mfma_f32_16x16x32_bf16(ah[i],  bl_[j], acc[i][j], 0, 0, 0);
                acc[i][j] = __builtin_amdgcn_mfma_f32_16x16x32_bf16(al_[i], bh[j],  acc[i][j], 0, 0, 0);
            }
        __syncthreads();
    }

    // epilogue: D frag (i,j) reg r -> row = wm*64+i*16+(lane>>4)*4+r, col = wn*64+j*16+(lane&15)
    const int crow0 = bm + wm * 64 + ((lane >> 4) << 2);
    const int ccol0 = bn + wn * 64 + (lane & 15);
    #pragma unroll
    for (int i = 0; i < 4; ++i)
        #pragma unroll
        for (int j = 0; j < 4; ++j)
            #pragma unroll
            for (int r = 0; r < 4; ++r)
                C[(size_t)(crow0 + i * 16 + r) * N + ccol0 + j * 16] = acc[i][j][r];
}

// ---------------- V column sums per (b, channel) ----------------
__global__ __launch_bounds__(256) void vsum_kernel(const float* __restrict__ v,
                                                   float* __restrict__ vsum) {
    const int b = blockIdx.x;
    const int c = blockIdx.y * 256 + threadIdx.x;
    const int s0 = blockIdx.z * 64;
    float a = 0.f;
    for (int s = s0; s < s0 + 64; ++s)
        a += v[((size_t)(b * S_LEN + s)) * D_MODEL + c];
    atomicAdd(&vsum[b * D_MODEL + c], a);
}

// ---------------- sparse rows (pos = 1 .. 2046) ----------------
// softmax over 2048 cols where only (deduped) idx cols are nonzero:
// out = (Vsum + sum_U (e^{s_j}-1) v_j) / (2048 - |U| + sum_U e^{s_j})
__global__ __launch_bounds__(768) void sparse_attn(
    const float* __restrict__ q, const float* __restrict__ k, const float* __restrict__ v,
    const float* __restrict__ vsum, const int* __restrict__ idx,
    float* __restrict__ ao) {
    const int i = blockIdx.x;        // 0..2045
    const int b = blockIdx.y;
    const int pos = i + 1;
    const int c = threadIdx.x;       // channel 0..767 (wave == head)

    int id[NI];
    #pragma unroll
    for (int j = 0; j < NI; ++j) id[j] = idx[i * NI + j];
    bool dup[NI];
    #pragma unroll
    for (int j = 0; j < NI; ++j) {
        bool d = false;
        #pragma unroll
        for (int j2 = 0; j2 < NI; ++j2)
            if (j2 < j) d = d || (id[j2] == id[j]);
        dup[j] = d;
    }

    const size_t rowbase = ((size_t)(b * S_LEN + pos)) * D_MODEL;
    const float qv = q[rowbase + c];

    // issue ALL 12 gathers up front -> independent, in flight together
    float kv[NI], vv[NI];
    #pragma unroll
    for (int j = 0; j < NI; ++j) {
        const size_t kb = ((size_t)(b * S_LEN + id[j])) * D_MODEL + c;
        kv[j] = k[kb];
        vv[j] = v[kb];
    }

    float p[NI];
    #pragma unroll
    for (int j = 0; j < NI; ++j) p[j] = qv * kv[j];

    // interleaved reduction trees (ILP across j)
    #pragma unroll
    for (int off = 32; off; off >>= 1) {
        #pragma unroll
        for (int j = 0; j < NI; ++j) p[j] += __shfl_xor(p[j], off);
    }

    float acc = vsum[b * D_MODEL + c];
    float Z = 0.f;
    int u = 0;
    #pragma unroll
    for (int j = 0; j < NI; ++j) {
        if (dup[j]) continue;                 // uniform branch (idx uniform per block)
        float e = expf(p[j] * 0.125f);        // 1/sqrt(64)
        Z += e;
        u += 1;
        acc += (e - 1.f) * vv[j];
    }
    Z += (float)(S_LEN - u);
    ao[rowbase + c] = acc / Z;
}

// ---------------- global rows: split-K partials ----------------
// grid: (NCH, 2, NH*BB); block 256. Each block: 256 keys of one (row,h,b).
// writes [m, E, acc[64]] per (rowblock, chunk)
__global__ __launch_bounds__(256) void global_attn_part(
    const float* __restrict__ q, const float* __restrict__ k, const float* __restrict__ v,
    float* __restrict__ part) {
    const int ch = blockIdx.x;
    const int rowsel = blockIdx.y;
    const int row = rowsel ? (S_LEN - 1) : 0;
    const int hb = blockIdx.z;
    const int h = hb % NH;
    const int b = hb / NH;
    const int tid = threadIdx.x;

    __shared__ float qs[HD];
    __shared__ float ps[CHK];
    __shared__ float red[8];
    __shared__ float pacc[256];

    if (tid < HD) qs[tid] = q[((size_t)(b * S_LEN + row)) * D_MODEL + h * HD + tid];
    __syncthreads();

    const int t = ch * CHK + tid;                    // this thread's key
    const float4* q4 = (const float4*)qs;
    const float4* kp = (const float4*)&k[((size_t)(b * S_LEN + t)) * D_MODEL + h * HD];
    float s = 0.f;
    #pragma unroll
    for (int dd = 0; dd < 16; ++dd) {
        float4 kk = kp[dd];
        float4 qq = q4[dd];
        s += qq.x * kk.x + qq.y * kk.y + qq.z * kk.z + qq.w * kk.w;
    }
    s *= 0.125f;

    // block max
    float m = s;
    #pragma unroll
    for (int off = 32; off; off >>= 1) m = fmaxf(m, __shfl_xor(m, off));
    if ((tid & 63) == 0) red[tid >> 6] = m;
    __syncthreads();
    m = fmaxf(fmaxf(red[0], red[1]), fmaxf(red[2], red[3]));

    float e = expf(s - m);
    ps[tid] = e;
    float zp = e;
    #pragma unroll
    for (int off = 32; off; off >>= 1) zp += __shfl_xor(zp, off);
    if ((tid & 63) == 0) red[4 + (tid >> 6)] = zp;
    __syncthreads();                                  // covers ps[] and red[]
    const float E = red[4] + red[5] + red[6] + red[7];

    // PV over this chunk
    const int d0 = tid & 63;
    const int grp = tid >> 6;
    float acc = 0.f;
    for (int tt = grp; tt < CHK; tt += 4)
        acc += ps[tt] * v[((size_t)(b * S_LEN + ch * CHK + tt)) * D_MODEL + h * HD + d0];
    pacc[tid] = acc;
    __syncthreads();
    if (tid < HD) {
        float o = pacc[tid] + pacc[64 + tid] + pacc[128 + tid] + pacc[192 + tid];
        float* pr = part + ((size_t)((hb * 2 + rowsel) * NCH + ch)) * (HD + 2);
        pr[2 + tid] = o;
        if (tid == 0) { pr[0] = m; pr[1] = E; }
    }
}

// finalize: 48 blocks x 64 threads
__global__ __launch_bounds__(64) void global_attn_fin(
    const float* __restrict__ part, float* __restrict__ ao) {
    const int rb = blockIdx.x;           // hb*2 + rowsel
    const int rowsel = rb & 1;
    const int hb = rb >> 1;
    const int h = hb % NH;
    const int b = hb / NH;
    const int row = rowsel ? (S_LEN - 1) : 0;
    const int d = threadIdx.x;

    const float* pr = part + (size_t)rb * NCH * (HD + 2);
    float M = -1e30f;
    #pragma unroll
    for (int c = 0; c < NCH; ++c) M = fmaxf(M, pr[c * (HD + 2)]);
    float Z = 0.f, acc = 0.f;
    #pragma unroll
    for (int c = 0; c < NCH; ++c) {
        float wgt = expf(pr[c * (HD + 2)] - M);
        Z   += pr[c * (HD + 2) + 1] * wgt;
        acc += pr[c * (HD + 2) + 2 + d] * wgt;
    }
    ao[((size_t)(b * S_LEN + row)) * D_MODEL + h * HD + d] = acc / Z;
}

// ---------------- launch ----------------
extern "C" void kernel_launch(void* const* d_in, const int* in_sizes, int n_in,
                              void* d_out, int out_size, void* d_ws, size_t ws_size,
                              hipStream_t stream) {
    const float* Q  = (const float*)d_in[0];
    const float* K  = (const float*)d_in[1];
    const float* V  = (const float*)d_in[2];
    const float* Wq = (const float*)d_in[3];
    const float* Wk = (const float*)d_in[4];
    const float* Wv = (const float*)d_in[5];
    const float* Wo = (const float*)d_in[6];
    const int*  idx = (const int*)d_in[7];
    float* out = (float*)d_out;

    const size_t NTOK = (size_t)BB * S_LEN;          // 4096
    const size_t SZ = NTOK * D_MODEL;                // 3145728 floats
    float* qb = (float*)d_ws;
    float* kb = qb + SZ;
    float* vb = kb + SZ;
    float* ao = vb + SZ;
    float* vs = ao + SZ;                             // BB*D_MODEL floats
    float* part = vs + (size_t)BB * D_MODEL;         // 48*NCH*(HD+2) floats

    hipMemsetAsync(vs, 0, BB * D_MODEL * sizeof(float), stream);

    {
        GemmArgs g0{Q, Wq, qb}, g1{K, Wk, kb}, g2{V, Wv, vb};
        dim3 grid(D_MODEL / GBN, (int)(NTOK / GBM), 3);
        mfma_gemm_nt<<<grid, 256, 0, stream>>>(g0, g1, g2, D_MODEL, D_MODEL);
    }
    vsum_kernel<<<dim3(BB, D_MODEL / 256, 32), 256, 0, stream>>>(vb, vs);
    sparse_attn<<<dim3(S2, BB), 768, 0, stream>>>(qb, kb, vb, vs, idx, ao);
    global_attn_part<<<dim3(NCH, 2, NH * BB), 256, 0, stream>>>(qb, kb, vb, part);
    global_attn_fin<<<dim3(2 * NH * BB), 64, 0, stream>>>(part, ao);
    {
        GemmArgs g{ao, Wo, out};
        dim3 grid(D_MODEL / GBN, (int)(NTOK / GBM), 1);
        mfma_gemm_nt<<<grid, 256, 0, stream>>>(g, g, g, D_MODEL, D_MODEL);
    }
}

// Round 4
// 214.749 us; speedup vs baseline: 2.7616x; 1.3795x over previous
//
#include <hip/hip_runtime.h>
#include <hip/hip_bf16.h>

#define S_LEN   2048
#define D_MODEL 768
#define NH      12
#define HD      64
#define NI      6
#define S2      2046
#define BB      2
#define NCH     8
#define CHK     256   // keys per chunk (NCH*CHK == S_LEN)

typedef unsigned short ushort_t;
typedef __attribute__((ext_vector_type(8))) short short8v;   // 8 bf16 = 16B
typedef __attribute__((ext_vector_type(4))) float f32x4;     // MFMA C/D frag

__device__ __forceinline__ unsigned short bf16_rne(float x) {
    union { float f; unsigned int u; } c; c.f = x;
    unsigned int u = c.u + 0x7fffu + ((c.u >> 16) & 1u);
    return (unsigned short)(u >> 16);
}
__device__ __forceinline__ float bf16_f(unsigned short h) {
    union { unsigned int u; float f; } c; c.u = ((unsigned int)h) << 16;
    return c.f;
}

__device__ __forceinline__ void gload16(const ushort_t* g, ushort_t* l) {
    __builtin_amdgcn_global_load_lds(
        (const __attribute__((address_space(1))) void*)g,
        (__attribute__((address_space(3))) void*)l, 16, 0, 0);
}

// ---------------- fp32 -> bf16 convert (8 elems/thread) ----------------
struct Cvt4 {
    const float* s0; const float* s1; const float* s2; const float* s3;
    ushort_t* d0; ushort_t* d1; ushort_t* d2; ushort_t* d3;
};

__global__ __launch_bounds__(256) void cvt_kernel(Cvt4 a, int n) {
    const float* s; ushort_t* d;
    switch (blockIdx.z) {
        case 0: s = a.s0; d = a.d0; break;
        case 1: s = a.s1; d = a.d1; break;
        case 2: s = a.s2; d = a.d2; break;
        default: s = a.s3; d = a.d3; break;
    }
    const int i = (blockIdx.x * 256 + threadIdx.x) * 8;
    float4 v0 = *(const float4*)&s[i];
    float4 v1 = *(const float4*)&s[i + 4];
    short8v o;
    o[0] = (short)bf16_rne(v0.x); o[1] = (short)bf16_rne(v0.y);
    o[2] = (short)bf16_rne(v0.z); o[3] = (short)bf16_rne(v0.w);
    o[4] = (short)bf16_rne(v1.x); o[5] = (short)bf16_rne(v1.y);
    o[6] = (short)bf16_rne(v1.z); o[7] = (short)bf16_rne(v1.w);
    *(short8v*)&d[i] = o;
}

// ---------------- bf16 MFMA NT GEMM: C[M,N] = A[M,K] * W[N,K]^T ----------
// 128x128 tile, BK=32, 2-phase double-buffered global_load_lds staging,
// XOR-swizzled LDS (linear dest + inverse-swizzled global source, rule 21).
struct GemmArgs { const ushort_t* A; const ushort_t* W; ushort_t* C; float* Cf; };

constexpr int GK = 768, GN = 768, GBK = 32, GNT = GK / GBK;   // 24 K-steps

__global__ __launch_bounds__(256) void bf16_gemm_nt(GemmArgs g0, GemmArgs g1, GemmArgs g2) {
    GemmArgs g = (blockIdx.z == 0) ? g0 : ((blockIdx.z == 1) ? g1 : g2);

    __shared__ ushort_t As[2][4096];   // 128 rows x 32 bf16, swizzled 16B blocks
    __shared__ ushort_t Bs[2][4096];

    const int tid  = threadIdx.x;
    const int lane = tid & 63;
    const int w    = tid >> 6;
    const int wm   = w & 1;
    const int wn   = w >> 1;
    const int bm   = blockIdx.y * 128;
    const int bn   = blockIdx.x * 128;
    const int fr   = lane & 15;
    const int blkr = lane >> 4;        // logical 16B-block (k/8)

    f32x4 acc[4][4];
    #pragma unroll
    for (int i = 0; i < 4; ++i)
        #pragma unroll
        for (int j = 0; j < 4; ++j)
            acc[i][j] = (f32x4){0.f, 0.f, 0.f, 0.f};

    // staging source addresses (inverse-swizzled so linear LDS == swizzled image)
    const int row0 = tid >> 2;                      // 0..63
    const int row1 = row0 + 64;                     // 64..127
    const int blk0 = (tid & 3) ^ ((row0 >> 1) & 3);
    const int blk1 = (tid & 3) ^ ((row1 >> 1) & 3);
    const ushort_t* Ag0 = g.A + (size_t)(bm + row0) * GK + blk0 * 8;
    const ushort_t* Ag1 = g.A + (size_t)(bm + row1) * GK + blk1 * 8;
    const ushort_t* Bg0 = g.W + (size_t)(bn + row0) * GK + blk0 * 8;
    const ushort_t* Bg1 = g.W + (size_t)(bn + row1) * GK + blk1 * 8;
    const int l0 = w * 512;            // wave-uniform LDS base (shorts), round 0
    const int l1 = 2048 + w * 512;     // round 1

    // fragment read offsets (swizzled), constant per lane
    int aoff[4], boff[4];
    #pragma unroll
    for (int i = 0; i < 4; ++i) {
        const int ra = wm * 64 + i * 16 + fr;
        aoff[i] = (ra * 4 + (blkr ^ ((ra >> 1) & 3))) * 8;
        const int rb = wn * 64 + i * 16 + fr;
        boff[i] = (rb * 4 + (blkr ^ ((rb >> 1) & 3))) * 8;
    }

    // prologue stage
    gload16(Ag0, &As[0][l0]); gload16(Ag1, &As[0][l1]);
    gload16(Bg0, &Bs[0][l0]); gload16(Bg1, &Bs[0][l1]);
    __syncthreads();

    int cur = 0;
    for (int kt = 0; kt < GNT; ++kt) {
        if (kt + 1 < GNT) {          // issue next-tile stage BEFORE compute
            const int ko = (kt + 1) * GBK;
            gload16(Ag0 + ko, &As[cur ^ 1][l0]); gload16(Ag1 + ko, &As[cur ^ 1][l1]);
            gload16(Bg0 + ko, &Bs[cur ^ 1][l0]); gload16(Bg1 + ko, &Bs[cur ^ 1][l1]);
        }
        short8v a[4], b[4];
        #pragma unroll
        for (int i = 0; i < 4; ++i) a[i] = *(const short8v*)&As[cur][aoff[i]];
        #pragma unroll
        for (int i = 0; i < 4; ++i) b[i] = *(const short8v*)&Bs[cur][boff[i]];
        #pragma unroll
        for (int i = 0; i < 4; ++i)
            #pragma unroll
            for (int j = 0; j < 4; ++j)
                acc[i][j] = __builtin_amdgcn_mfma_f32_16x16x32_bf16(a[i], b[j], acc[i][j], 0, 0, 0);
        __syncthreads();             // drains vmcnt (stage landed) + lgkm
        cur ^= 1;
    }

    const int crow0 = bm + wm * 64 + ((lane >> 4) << 2);
    const int ccol0 = bn + wn * 64 + fr;
    if (g.Cf) {
        #pragma unroll
        for (int i = 0; i < 4; ++i)
            #pragma unroll
            for (int j = 0; j < 4; ++j)
                #pragma unroll
                for (int r = 0; r < 4; ++r)
                    g.Cf[(size_t)(crow0 + i * 16 + r) * GN + ccol0 + j * 16] = acc[i][j][r];
    } else {
        #pragma unroll
        for (int i = 0; i < 4; ++i)
            #pragma unroll
            for (int j = 0; j < 4; ++j)
                #pragma unroll
                for (int r = 0; r < 4; ++r)
                    g.C[(size_t)(crow0 + i * 16 + r) * GN + ccol0 + j * 16] = bf16_rne(acc[i][j][r]);
    }
}

// ---------------- V column sums per (b, channel) ----------------
__global__ __launch_bounds__(256) void vsum_kernel(const ushort_t* __restrict__ v,
                                                   float* __restrict__ vsum) {
    const int b = blockIdx.x;
    const int c = blockIdx.y * 256 + threadIdx.x;
    const int s0 = blockIdx.z * 64;
    float a = 0.f;
    for (int s = s0; s < s0 + 64; ++s)
        a += bf16_f(v[((size_t)(b * S_LEN + s)) * D_MODEL + c]);
    atomicAdd(&vsum[b * D_MODEL + c], a);
}

// ---------------- sparse rows (pos = 1 .. 2046) ----------------
__global__ __launch_bounds__(768) void sparse_attn(
    const ushort_t* __restrict__ q, const ushort_t* __restrict__ k, const ushort_t* __restrict__ v,
    const float* __restrict__ vsum, const int* __restrict__ idx,
    ushort_t* __restrict__ ao) {
    const int i = blockIdx.x;        // 0..2045
    const int b = blockIdx.y;
    const int pos = i + 1;
    const int c = threadIdx.x;       // channel 0..767 (wave == head)

    int id[NI];
    #pragma unroll
    for (int j = 0; j < NI; ++j) id[j] = idx[i * NI + j];
    bool dup[NI];
    #pragma unroll
    for (int j = 0; j < NI; ++j) {
        bool d = false;
        #pragma unroll
        for (int j2 = 0; j2 < NI; ++j2)
            if (j2 < j) d = d || (id[j2] == id[j]);
        dup[j] = d;
    }

    const size_t rowbase = ((size_t)(b * S_LEN + pos)) * D_MODEL;
    const float qv = bf16_f(q[rowbase + c]);

    float kv[NI], vv[NI];
    #pragma unroll
    for (int j = 0; j < NI; ++j) {
        const size_t kb = ((size_t)(b * S_LEN + id[j])) * D_MODEL + c;
        kv[j] = bf16_f(k[kb]);
        vv[j] = bf16_f(v[kb]);
    }

    float p[NI];
    #pragma unroll
    for (int j = 0; j < NI; ++j) p[j] = qv * kv[j];

    #pragma unroll
    for (int off = 32; off; off >>= 1) {
        #pragma unroll
        for (int j = 0; j < NI; ++j) p[j] += __shfl_xor(p[j], off);
    }

    float acc = vsum[b * D_MODEL + c];
    float Z = 0.f;
    int u = 0;
    #pragma unroll
    for (int j = 0; j < NI; ++j) {
        if (dup[j]) continue;
        float e = expf(p[j] * 0.125f);
        Z += e;
        u += 1;
        acc += (e - 1.f) * vv[j];
    }
    Z += (float)(S_LEN - u);
    ao[rowbase + c] = bf16_rne(acc / Z);
}

// ---------------- global rows: split-K partials ----------------
__global__ __launch_bounds__(256) void global_attn_part(
    const ushort_t* __restrict__ q, const ushort_t* __restrict__ k, const ushort_t* __restrict__ v,
    float* __restrict__ part) {
    const int ch = blockIdx.x;
    const int rowsel = blockIdx.y;
    const int row = rowsel ? (S_LEN - 1) : 0;
    const int hb = blockIdx.z;
    const int h = hb % NH;
    const int b = hb / NH;
    const int tid = threadIdx.x;

    __shared__ float qs[HD];
    __shared__ float ps[CHK];
    __shared__ float red[8];
    __shared__ float pacc[256];

    if (tid < HD) qs[tid] = bf16_f(q[((size_t)(b * S_LEN + row)) * D_MODEL + h * HD + tid]);
    __syncthreads();

    const int t = ch * CHK + tid;
    const ushort_t* kp = &k[((size_t)(b * S_LEN + t)) * D_MODEL + h * HD];
    float s = 0.f;
    #pragma unroll
    for (int dd = 0; dd < 8; ++dd) {
        short8v kk = *(const short8v*)&kp[dd * 8];
        #pragma unroll
        for (int e = 0; e < 8; ++e)
            s += qs[dd * 8 + e] * bf16_f((unsigned short)kk[e]);
    }
    s *= 0.125f;

    float m = s;
    #pragma unroll
    for (int off = 32; off; off >>= 1) m = fmaxf(m, __shfl_xor(m, off));
    if ((tid & 63) == 0) red[tid >> 6] = m;
    __syncthreads();
    m = fmaxf(fmaxf(red[0], red[1]), fmaxf(red[2], red[3]));

    float e = expf(s - m);
    ps[tid] = e;
    float zp = e;
    #pragma unroll
    for (int off = 32; off; off >>= 1) zp += __shfl_xor(zp, off);
    if ((tid & 63) == 0) red[4 + (tid >> 6)] = zp;
    __syncthreads();
    const float E = red[4] + red[5] + red[6] + red[7];

    const int d0 = tid & 63;
    const int grp = tid >> 6;
    float acc = 0.f;
    for (int tt = grp; tt < CHK; tt += 4)
        acc += ps[tt] * bf16_f(v[((size_t)(b * S_LEN + ch * CHK + tt)) * D_MODEL + h * HD + d0]);
    pacc[tid] = acc;
    __syncthreads();
    if (tid < HD) {
        float o = pacc[tid] + pacc[64 + tid] + pacc[128 + tid] + pacc[192 + tid];
        float* pr = part + ((size_t)((hb * 2 + rowsel) * NCH + ch)) * (HD + 2);
        pr[2 + tid] = o;
        if (tid == 0) { pr[0] = m; pr[1] = E; }
    }
}

__global__ __launch_bounds__(64) void global_attn_fin(
    const float* __restrict__ part, ushort_t* __restrict__ ao) {
    const int rb = blockIdx.x;
    const int rowsel = rb & 1;
    const int hb = rb >> 1;
    const int h = hb % NH;
    const int b = hb / NH;
    const int row = rowsel ? (S_LEN - 1) : 0;
    const int d = threadIdx.x;

    const float* pr = part + (size_t)rb * NCH * (HD + 2);
    float M = -1e30f;
    #pragma unroll
    for (int c = 0; c < NCH; ++c) M = fmaxf(M, pr[c * (HD + 2)]);
    float Z = 0.f, acc = 0.f;
    #pragma unroll
    for (int c = 0; c < NCH; ++c) {
        float wgt = expf(pr[c * (HD + 2)] - M);
        Z   += pr[c * (HD + 2) + 1] * wgt;
        acc += pr[c * (HD + 2) + 2 + d] * wgt;
    }
    ao[((size_t)(b * S_LEN + row)) * D_MODEL + h * HD + d] = bf16_rne(acc / Z);
}

// ---------------- launch ----------------
extern "C" void kernel_launch(void* const* d_in, const int* in_sizes, int n_in,
                              void* d_out, int out_size, void* d_ws, size_t ws_size,
                              hipStream_t stream) {
    const float* Q  = (const float*)d_in[0];
    const float* K  = (const float*)d_in[1];
    const float* V  = (const float*)d_in[2];
    const float* Wq = (const float*)d_in[3];
    const float* Wk = (const float*)d_in[4];
    const float* Wv = (const float*)d_in[5];
    const float* Wo = (const float*)d_in[6];
    const int*  idx = (const int*)d_in[7];
    float* out = (float*)d_out;

    const size_t SZ  = (size_t)BB * S_LEN * D_MODEL;   // 3,145,728
    const size_t WSZ = (size_t)D_MODEL * D_MODEL;      // 589,824

    ushort_t* Qc  = (ushort_t*)d_ws;
    ushort_t* Kc  = Qc  + SZ;
    ushort_t* Vc  = Kc  + SZ;
    ushort_t* Wqc = Vc  + SZ;
    ushort_t* Wkc = Wqc + WSZ;
    ushort_t* Wvc = Wkc + WSZ;
    ushort_t* Woc = Wvc + WSZ;
    ushort_t* qb  = Woc + WSZ;
    ushort_t* kb  = qb  + SZ;
    ushort_t* vb  = kb  + SZ;
    ushort_t* ao  = vb  + SZ;
    float* vs   = (float*)(ao + SZ);
    float* part = vs + BB * D_MODEL;

    // convert inputs + weights to bf16
    {
        Cvt4 a{Q, K, V, Q, Qc, Kc, Vc, Qc};
        cvt_kernel<<<dim3((unsigned)(SZ / 2048), 1, 3), 256, 0, stream>>>(a, (int)SZ);
        Cvt4 b{Wq, Wk, Wv, Wo, Wqc, Wkc, Wvc, Woc};
        cvt_kernel<<<dim3((unsigned)(WSZ / 2048), 1, 4), 256, 0, stream>>>(b, (int)WSZ);
    }

    hipMemsetAsync(vs, 0, BB * D_MODEL * sizeof(float), stream);

    {   // Q,K,V projections (bf16 out)
        GemmArgs g0{Qc, Wqc, qb, nullptr}, g1{Kc, Wkc, kb, nullptr}, g2{Vc, Wvc, vb, nullptr};
        bf16_gemm_nt<<<dim3(D_MODEL / 128, BB * S_LEN / 128, 3), 256, 0, stream>>>(g0, g1, g2);
    }
    vsum_kernel<<<dim3(BB, D_MODEL / 256, 32), 256, 0, stream>>>(vb, vs);
    sparse_attn<<<dim3(S2, BB), 768, 0, stream>>>(qb, kb, vb, vs, idx, ao);
    global_attn_part<<<dim3(NCH, 2, NH * BB), 256, 0, stream>>>(qb, kb, vb, part);
    global_attn_fin<<<dim3(2 * NH * BB), 64, 0, stream>>>(part, ao);
    {   // output projection (fp32 out)
        GemmArgs g{ao, Woc, nullptr, out};
        bf16_gemm_nt<<<dim3(D_MODEL / 128, BB * S_LEN / 128, 1), 256, 0, stream>>>(g, g, g);
    }
}

// Round 5
// 214.529 us; speedup vs baseline: 2.7644x; 1.0010x over previous
//
#include <hip/hip_runtime.h>
#include <hip/hip_bf16.h>

#define S_LEN   2048
#define D_MODEL 768
#define NH      12
#define HD      64
#define NI      6
#define S2      2046
#define BB      2
#define NCH     8
#define CHK     256   // keys per chunk (NCH*CHK == S_LEN)

typedef unsigned short ushort_t;
typedef __attribute__((ext_vector_type(8))) short short8v;   // 8 bf16 = 16B
typedef __attribute__((ext_vector_type(4))) float f32x4;     // MFMA C/D frag

__device__ __forceinline__ unsigned short bf16_rne(float x) {
    union { float f; unsigned int u; } c; c.f = x;
    unsigned int u = c.u + 0x7fffu + ((c.u >> 16) & 1u);
    return (unsigned short)(u >> 16);
}
__device__ __forceinline__ float bf16_f(unsigned short h) {
    union { unsigned int u; float f; } c; c.u = ((unsigned int)h) << 16;
    return c.f;
}

__device__ __forceinline__ void gload16(const ushort_t* g, ushort_t* l) {
    __builtin_amdgcn_global_load_lds(
        (const __attribute__((address_space(1))) void*)g,
        (__attribute__((address_space(3))) void*)l, 16, 0, 0);
}

// ---------------- fp32 -> bf16 convert (8 elems/thread) ----------------
struct Cvt4 {
    const float* s0; const float* s1; const float* s2; const float* s3;
    ushort_t* d0; ushort_t* d1; ushort_t* d2; ushort_t* d3;
};

__global__ __launch_bounds__(256) void cvt_kernel(Cvt4 a, int n) {
    const float* s; ushort_t* d;
    switch (blockIdx.z) {
        case 0: s = a.s0; d = a.d0; break;
        case 1: s = a.s1; d = a.d1; break;
        case 2: s = a.s2; d = a.d2; break;
        default: s = a.s3; d = a.d3; break;
    }
    const int i = (blockIdx.x * 256 + threadIdx.x) * 8;
    float4 v0 = *(const float4*)&s[i];
    float4 v1 = *(const float4*)&s[i + 4];
    short8v o;
    o[0] = (short)bf16_rne(v0.x); o[1] = (short)bf16_rne(v0.y);
    o[2] = (short)bf16_rne(v0.z); o[3] = (short)bf16_rne(v0.w);
    o[4] = (short)bf16_rne(v1.x); o[5] = (short)bf16_rne(v1.y);
    o[6] = (short)bf16_rne(v1.z); o[7] = (short)bf16_rne(v1.w);
    *(short8v*)&d[i] = o;
}

// ---------------- bf16 MFMA NT GEMM: C[M,N] = A[M,K] * W[N,K]^T ----------
// 128x128 tile, BK=32. 3-buffer LDS ring, depth-2 prefetch via
// global_load_lds with COUNTED s_waitcnt vmcnt(4) + raw s_barrier
// (never drains to 0 in main loop -> loads stay in flight across barriers).
struct GemmArgs { const ushort_t* A; const ushort_t* W; ushort_t* C; float* Cf; };

constexpr int GK = 768, GN = 768, GBK = 32, GNT = GK / GBK;   // 24 K-steps

__global__ __launch_bounds__(256) void bf16_gemm_nt(GemmArgs g0, GemmArgs g1, GemmArgs g2) {
    GemmArgs g = (blockIdx.z == 0) ? g0 : ((blockIdx.z == 1) ? g1 : g2);

    __shared__ ushort_t As[3][4096];   // 128 rows x 32 bf16, swizzled 16B blocks
    __shared__ ushort_t Bs[3][4096];

    const int tid  = threadIdx.x;
    const int lane = tid & 63;
    const int w    = tid >> 6;
    const int wm   = w & 1;
    const int wn   = w >> 1;
    const int bm   = blockIdx.y * 128;
    const int bn   = blockIdx.x * 128;
    const int fr   = lane & 15;
    const int blkr = lane >> 4;        // logical 16B-block (k/8)

    f32x4 acc[4][4];
    #pragma unroll
    for (int i = 0; i < 4; ++i)
        #pragma unroll
        for (int j = 0; j < 4; ++j)
            acc[i][j] = (f32x4){0.f, 0.f, 0.f, 0.f};

    // staging source addresses (inverse-swizzled so linear LDS == swizzled image)
    const int row0 = tid >> 2;                      // 0..63
    const int row1 = row0 + 64;                     // 64..127
    const int blk0 = (tid & 3) ^ ((row0 >> 1) & 3);
    const int blk1 = (tid & 3) ^ ((row1 >> 1) & 3);
    const ushort_t* Ag0 = g.A + (size_t)(bm + row0) * GK + blk0 * 8;
    const ushort_t* Ag1 = g.A + (size_t)(bm + row1) * GK + blk1 * 8;
    const ushort_t* Bg0 = g.W + (size_t)(bn + row0) * GK + blk0 * 8;
    const ushort_t* Bg1 = g.W + (size_t)(bn + row1) * GK + blk1 * 8;
    const int l0 = w * 512;            // wave-uniform LDS base (shorts), half 0
    const int l1 = 2048 + w * 512;     // half 1

    // fragment read offsets (swizzled), constant per lane
    int aoff[4], boff[4];
    #pragma unroll
    for (int i = 0; i < 4; ++i) {
        const int ra = wm * 64 + i * 16 + fr;
        aoff[i] = (ra * 4 + (blkr ^ ((ra >> 1) & 3))) * 8;
        const int rb = wn * 64 + i * 16 + fr;
        boff[i] = (rb * 4 + (blkr ^ ((rb >> 1) & 3))) * 8;
    }

    // prologue: stage tiles t=0 (buf0) and t=1 (buf1) -> 8 loads in flight
    gload16(Ag0, &As[0][l0]); gload16(Ag1, &As[0][l1]);
    gload16(Bg0, &Bs[0][l0]); gload16(Bg1, &Bs[0][l1]);
    gload16(Ag0 + GBK, &As[1][l0]); gload16(Ag1 + GBK, &As[1][l1]);
    gload16(Bg0 + GBK, &Bs[1][l0]); gload16(Bg1 + GBK, &Bs[1][l1]);

    for (int t = 0; t < GNT; ++t) {
        // wait: stage(t) landed for THIS wave (stage(t+1) may stay in flight),
        // then barrier publishes across all waves.
        if (t < GNT - 1) asm volatile("s_waitcnt vmcnt(4)" ::: "memory");
        else             asm volatile("s_waitcnt vmcnt(0)" ::: "memory");
        __builtin_amdgcn_s_barrier();

        if (t + 2 < GNT) {           // stage(t+2) into the buffer read at t-1
            const int ko = (t + 2) * GBK;
            const int nb = (t + 2) % 3;
            gload16(Ag0 + ko, &As[nb][l0]); gload16(Ag1 + ko, &As[nb][l1]);
            gload16(Bg0 + ko, &Bs[nb][l0]); gload16(Bg1 + ko, &Bs[nb][l1]);
        }

        const ushort_t* as = As[t % 3];
        const ushort_t* bs = Bs[t % 3];
        short8v a[4], b[4];
        #pragma unroll
        for (int i = 0; i < 4; ++i) a[i] = *(const short8v*)&as[aoff[i]];
        #pragma unroll
        for (int i = 0; i < 4; ++i) b[i] = *(const short8v*)&bs[boff[i]];
        #pragma unroll
        for (int i = 0; i < 4; ++i)
            #pragma unroll
            for (int j = 0; j < 4; ++j)
                acc[i][j] = __builtin_amdgcn_mfma_f32_16x16x32_bf16(a[i], b[j], acc[i][j], 0, 0, 0);
    }

    const int crow0 = bm + wm * 64 + ((lane >> 4) << 2);
    const int ccol0 = bn + wn * 64 + fr;
    if (g.Cf) {
        #pragma unroll
        for (int i = 0; i < 4; ++i)
            #pragma unroll
            for (int j = 0; j < 4; ++j)
                #pragma unroll
                for (int r = 0; r < 4; ++r)
                    g.Cf[(size_t)(crow0 + i * 16 + r) * GN + ccol0 + j * 16] = acc[i][j][r];
    } else {
        #pragma unroll
        for (int i = 0; i < 4; ++i)
            #pragma unroll
            for (int j = 0; j < 4; ++j)
                #pragma unroll
                for (int r = 0; r < 4; ++r)
                    g.C[(size_t)(crow0 + i * 16 + r) * GN + ccol0 + j * 16] = bf16_rne(acc[i][j][r]);
    }
}

// ---------------- V column sums per (b, channel) ----------------
__global__ __launch_bounds__(256) void vsum_kernel(const ushort_t* __restrict__ v,
                                                   float* __restrict__ vsum) {
    const int b = blockIdx.x;
    const int c = blockIdx.y * 256 + threadIdx.x;
    const int s0 = blockIdx.z * 64;
    float a = 0.f;
    for (int s = s0; s < s0 + 64; ++s)
        a += bf16_f(v[((size_t)(b * S_LEN + s)) * D_MODEL + c]);
    atomicAdd(&vsum[b * D_MODEL + c], a);
}

// ---------------- sparse rows (pos = 1 .. 2046) ----------------
__global__ __launch_bounds__(768) void sparse_attn(
    const ushort_t* __restrict__ q, const ushort_t* __restrict__ k, const ushort_t* __restrict__ v,
    const float* __restrict__ vsum, const int* __restrict__ idx,
    ushort_t* __restrict__ ao) {
    const int i = blockIdx.x;        // 0..2045
    const int b = blockIdx.y;
    const int pos = i + 1;
    const int c = threadIdx.x;       // channel 0..767 (wave == head)

    int id[NI];
    #pragma unroll
    for (int j = 0; j < NI; ++j) id[j] = idx[i * NI + j];
    bool dup[NI];
    #pragma unroll
    for (int j = 0; j < NI; ++j) {
        bool d = false;
        #pragma unroll
        for (int j2 = 0; j2 < NI; ++j2)
            if (j2 < j) d = d || (id[j2] == id[j]);
        dup[j] = d;
    }

    const size_t rowbase = ((size_t)(b * S_LEN + pos)) * D_MODEL;
    const float qv = bf16_f(q[rowbase + c]);

    float kv[NI], vv[NI];
    #pragma unroll
    for (int j = 0; j < NI; ++j) {
        const size_t kb = ((size_t)(b * S_LEN + id[j])) * D_MODEL + c;
        kv[j] = bf16_f(k[kb]);
        vv[j] = bf16_f(v[kb]);
    }

    float p[NI];
    #pragma unroll
    for (int j = 0; j < NI; ++j) p[j] = qv * kv[j];

    #pragma unroll
    for (int off = 32; off; off >>= 1) {
        #pragma unroll
        for (int j = 0; j < NI; ++j) p[j] += __shfl_xor(p[j], off);
    }

    float acc = vsum[b * D_MODEL + c];
    float Z = 0.f;
    int u = 0;
    #pragma unroll
    for (int j = 0; j < NI; ++j) {
        if (dup[j]) continue;
        float e = expf(p[j] * 0.125f);
        Z += e;
        u += 1;
        acc += (e - 1.f) * vv[j];
    }
    Z += (float)(S_LEN - u);
    ao[rowbase + c] = bf16_rne(acc / Z);
}

// ---------------- global rows: split-K partials ----------------
__global__ __launch_bounds__(256) void global_attn_part(
    const ushort_t* __restrict__ q, const ushort_t* __restrict__ k, const ushort_t* __restrict__ v,
    float* __restrict__ part) {
    const int ch = blockIdx.x;
    const int rowsel = blockIdx.y;
    const int row = rowsel ? (S_LEN - 1) : 0;
    const int hb = blockIdx.z;
    const int h = hb % NH;
    const int b = hb / NH;
    const int tid = threadIdx.x;

    __shared__ float qs[HD];
    __shared__ float ps[CHK];
    __shared__ float red[8];
    __shared__ float pacc[256];

    if (tid < HD) qs[tid] = bf16_f(q[((size_t)(b * S_LEN + row)) * D_MODEL + h * HD + tid]);
    __syncthreads();

    const int t = ch * CHK + tid;
    const ushort_t* kp = &k[((size_t)(b * S_LEN + t)) * D_MODEL + h * HD];
    float s = 0.f;
    #pragma unroll
    for (int dd = 0; dd < 8; ++dd) {
        short8v kk = *(const short8v*)&kp[dd * 8];
        #pragma unroll
        for (int e = 0; e < 8; ++e)
            s += qs[dd * 8 + e] * bf16_f((unsigned short)kk[e]);
    }
    s *= 0.125f;

    float m = s;
    #pragma unroll
    for (int off = 32; off; off >>= 1) m = fmaxf(m, __shfl_xor(m, off));
    if ((tid & 63) == 0) red[tid >> 6] = m;
    __syncthreads();
    m = fmaxf(fmaxf(red[0], red[1]), fmaxf(red[2], red[3]));

    float e = expf(s - m);
    ps[tid] = e;
    float zp = e;
    #pragma unroll
    for (int off = 32; off; off >>= 1) zp += __shfl_xor(zp, off);
    if ((tid & 63) == 0) red[4 + (tid >> 6)] = zp;
    __syncthreads();
    const float E = red[4] + red[5] + red[6] + red[7];

    const int d0 = tid & 63;
    const int grp = tid >> 6;
    float acc = 0.f;
    for (int tt = grp; tt < CHK; tt += 4)
        acc += ps[tt] * bf16_f(v[((size_t)(b * S_LEN + ch * CHK + tt)) * D_MODEL + h * HD + d0]);
    pacc[tid] = acc;
    __syncthreads();
    if (tid < HD) {
        float o = pacc[tid] + pacc[64 + tid] + pacc[128 + tid] + pacc[192 + tid];
        float* pr = part + ((size_t)((hb * 2 + rowsel) * NCH + ch)) * (HD + 2);
        pr[2 + tid] = o;
        if (tid == 0) { pr[0] = m; pr[1] = E; }
    }
}

__global__ __launch_bounds__(64) void global_attn_fin(
    const float* __restrict__ part, ushort_t* __restrict__ ao) {
    const int rb = blockIdx.x;
    const int rowsel = rb & 1;
    const int hb = rb >> 1;
    const int h = hb % NH;
    const int b = hb / NH;
    const int row = rowsel ? (S_LEN - 1) : 0;
    const int d = threadIdx.x;

    const float* pr = part + (size_t)rb * NCH * (HD + 2);
    float M = -1e30f;
    #pragma unroll
    for (int c = 0; c < NCH; ++c) M = fmaxf(M, pr[c * (HD + 2)]);
    float Z = 0.f, acc = 0.f;
    #pragma unroll
    for (int c = 0; c < NCH; ++c) {
        float wgt = expf(pr[c * (HD + 2)] - M);
        Z   += pr[c * (HD + 2) + 1] * wgt;
        acc += pr[c * (HD + 2) + 2 + d] * wgt;
    }
    ao[((size_t)(b * S_LEN + row)) * D_MODEL + h * HD + d] = bf16_rne(acc / Z);
}

// ---------------- launch ----------------
extern "C" void kernel_launch(void* const* d_in, const int* in_sizes, int n_in,
                              void* d_out, int out_size, void* d_ws, size_t ws_size,
                              hipStream_t stream) {
    const float* Q  = (const float*)d_in[0];
    const float* K  = (const float*)d_in[1];
    const float* V  = (const float*)d_in[2];
    const float* Wq = (const float*)d_in[3];
    const float* Wk = (const float*)d_in[4];
    const float* Wv = (const float*)d_in[5];
    const float* Wo = (const float*)d_in[6];
    const int*  idx = (const int*)d_in[7];
    float* out = (float*)d_out;

    const size_t SZ  = (size_t)BB * S_LEN * D_MODEL;   // 3,145,728
    const size_t WSZ = (size_t)D_MODEL * D_MODEL;      // 589,824

    ushort_t* Qc  = (ushort_t*)d_ws;
    ushort_t* Kc  = Qc  + SZ;
    ushort_t* Vc  = Kc  + SZ;
    ushort_t* Wqc = Vc  + SZ;
    ushort_t* Wkc = Wqc + WSZ;
    ushort_t* Wvc = Wkc + WSZ;
    ushort_t* Woc = Wvc + WSZ;
    ushort_t* qb  = Woc + WSZ;
    ushort_t* kb  = qb  + SZ;
    ushort_t* vb  = kb  + SZ;
    ushort_t* ao  = vb  + SZ;
    float* vs   = (float*)(ao + SZ);
    float* part = vs + BB * D_MODEL;

    // convert inputs + weights to bf16
    {
        Cvt4 a{Q, K, V, Q, Qc, Kc, Vc, Qc};
        cvt_kernel<<<dim3((unsigned)(SZ / 2048), 1, 3), 256, 0, stream>>>(a, (int)SZ);
        Cvt4 b{Wq, Wk, Wv, Wo, Wqc, Wkc, Wvc, Woc};
        cvt_kernel<<<dim3((unsigned)(WSZ / 2048), 1, 4), 256, 0, stream>>>(b, (int)WSZ);
    }

    hipMemsetAsync(vs, 0, BB * D_MODEL * sizeof(float), stream);

    {   // Q,K,V projections (bf16 out)
        GemmArgs g0{Qc, Wqc, qb, nullptr}, g1{Kc, Wkc, kb, nullptr}, g2{Vc, Wvc, vb, nullptr};
        bf16_gemm_nt<<<dim3(D_MODEL / 128, BB * S_LEN / 128, 3), 256, 0, stream>>>(g0, g1, g2);
    }
    vsum_kernel<<<dim3(BB, D_MODEL / 256, 32), 256, 0, stream>>>(vb, vs);
    sparse_attn<<<dim3(S2, BB), 768, 0, stream>>>(qb, kb, vb, vs, idx, ao);
    global_attn_part<<<dim3(NCH, 2, NH * BB), 256, 0, stream>>>(qb, kb, vb, part);
    global_attn_fin<<<dim3(2 * NH * BB), 64, 0, stream>>>(part, ao);
    {   // output projection (fp32 out)
        GemmArgs g{ao, Woc, nullptr, out};
        bf16_gemm_nt<<<dim3(D_MODEL / 128, BB * S_LEN / 128, 1), 256, 0, stream>>>(g, g, g);
    }
}

// Round 6
// 198.221 us; speedup vs baseline: 2.9919x; 1.0823x over previous
//
#include <hip/hip_runtime.h>
#include <hip/hip_bf16.h>

#define S_LEN   2048
#define D_MODEL 768
#define NH      12
#define HD      64
#define NI      6
#define S2      2046
#define BB      2
#define NCH     8
#define CHK     256   // keys per chunk (NCH*CHK == S_LEN)

typedef unsigned short ushort_t;
typedef __attribute__((ext_vector_type(8))) short short8v;   // 8 bf16 = 16B
typedef __attribute__((ext_vector_type(4))) float f32x4;     // MFMA C/D frag

__device__ __forceinline__ unsigned short bf16_rne(float x) {
    union { float f; unsigned int u; } c; c.f = x;
    unsigned int u = c.u + 0x7fffu + ((c.u >> 16) & 1u);
    return (unsigned short)(u >> 16);
}
__device__ __forceinline__ float bf16_f(unsigned short h) {
    union { unsigned int u; float f; } c; c.u = ((unsigned int)h) << 16;
    return c.f;
}

__device__ __forceinline__ void gload16(const ushort_t* g, ushort_t* l) {
    __builtin_amdgcn_global_load_lds(
        (const __attribute__((address_space(1))) void*)g,
        (__attribute__((address_space(3))) void*)l, 16, 0, 0);
}

// -------- combined fp32->bf16 convert (QKV + weights) + vs zero-fill --------
// z=0,1,2: Q,K,V (SZ elems each); z=3: 4 weight mats flat (4*WSZ); z=4: zero vs
struct CvtAll {
    const float* Q; const float* K; const float* V;
    const float* Wq; const float* Wk; const float* Wv; const float* Wo;
    ushort_t* Qc; ushort_t* Kc; ushort_t* Vc;
    ushort_t* Wqc; ushort_t* Wkc; ushort_t* Wvc; ushort_t* Woc;
    float* vs;
};

__global__ __launch_bounds__(256) void cvt_all(CvtAll a) {
    const int z = blockIdx.z;
    const int tid = threadIdx.x;
    if (z == 4) {
        if (blockIdx.x == 0)
            for (int i = tid; i < BB * D_MODEL; i += 256) a.vs[i] = 0.f;
        return;
    }
    const float* s; ushort_t* d; long i;
    if (z < 3) {
        s = (z == 0) ? a.Q : (z == 1) ? a.K : a.V;
        d = (z == 0) ? a.Qc : (z == 1) ? a.Kc : a.Vc;
        i = ((long)blockIdx.x * 256 + tid) * 8;
    } else {
        const long WSZ = (long)D_MODEL * D_MODEL;
        long f = ((long)blockIdx.x * 256 + tid) * 8;
        if (f >= 4 * WSZ) return;
        const int which = (int)(f / WSZ);
        i = f % WSZ;
        s = (which == 0) ? a.Wq : (which == 1) ? a.Wk : (which == 2) ? a.Wv : a.Wo;
        d = (which == 0) ? a.Wqc : (which == 1) ? a.Wkc : (which == 2) ? a.Wvc : a.Woc;
    }
    float4 v0 = *(const float4*)&s[i];
    float4 v1 = *(const float4*)&s[i + 4];
    short8v o;
    o[0] = (short)bf16_rne(v0.x); o[1] = (short)bf16_rne(v0.y);
    o[2] = (short)bf16_rne(v0.z); o[3] = (short)bf16_rne(v0.w);
    o[4] = (short)bf16_rne(v1.x); o[5] = (short)bf16_rne(v1.y);
    o[6] = (short)bf16_rne(v1.z); o[7] = (short)bf16_rne(v1.w);
    *(short8v*)&d[i] = o;
}

// ---------------- bf16 MFMA NT GEMM: C[M,N] = A[M,K] * W[N,K]^T ----------
// 128x128 tile, BK=32, 3-buffer ring, depth-2 prefetch, counted vmcnt.
// Optional fused column-sum epilogue (vs != nullptr) for the V projection.
struct GemmArgs { const ushort_t* A; const ushort_t* W; ushort_t* C; float* Cf; float* vs; };

constexpr int GK = 768, GN = 768, GBK = 32, GNT = GK / GBK;   // 24 K-steps

__global__ __launch_bounds__(256) void bf16_gemm_nt(GemmArgs g0, GemmArgs g1, GemmArgs g2) {
    GemmArgs g = (blockIdx.z == 0) ? g0 : ((blockIdx.z == 1) ? g1 : g2);

    __shared__ ushort_t As[3][4096];   // 128 rows x 32 bf16, swizzled 16B blocks
    __shared__ ushort_t Bs[3][4096];

    const int tid  = threadIdx.x;
    const int lane = tid & 63;
    const int w    = tid >> 6;
    const int wm   = w & 1;
    const int wn   = w >> 1;
    const int bm   = blockIdx.y * 128;
    const int bn   = blockIdx.x * 128;
    const int fr   = lane & 15;
    const int blkr = lane >> 4;        // logical 16B-block (k/8)

    f32x4 acc[4][4];
    #pragma unroll
    for (int i = 0; i < 4; ++i)
        #pragma unroll
        for (int j = 0; j < 4; ++j)
            acc[i][j] = (f32x4){0.f, 0.f, 0.f, 0.f};

    const int row0 = tid >> 2;                      // 0..63
    const int row1 = row0 + 64;                     // 64..127
    const int blk0 = (tid & 3) ^ ((row0 >> 1) & 3);
    const int blk1 = (tid & 3) ^ ((row1 >> 1) & 3);
    const ushort_t* Ag0 = g.A + (size_t)(bm + row0) * GK + blk0 * 8;
    const ushort_t* Ag1 = g.A + (size_t)(bm + row1) * GK + blk1 * 8;
    const ushort_t* Bg0 = g.W + (size_t)(bn + row0) * GK + blk0 * 8;
    const ushort_t* Bg1 = g.W + (size_t)(bn + row1) * GK + blk1 * 8;
    const int l0 = w * 512;
    const int l1 = 2048 + w * 512;

    int aoff[4], boff[4];
    #pragma unroll
    for (int i = 0; i < 4; ++i) {
        const int ra = wm * 64 + i * 16 + fr;
        aoff[i] = (ra * 4 + (blkr ^ ((ra >> 1) & 3))) * 8;
        const int rb = wn * 64 + i * 16 + fr;
        boff[i] = (rb * 4 + (blkr ^ ((rb >> 1) & 3))) * 8;
    }

    gload16(Ag0, &As[0][l0]); gload16(Ag1, &As[0][l1]);
    gload16(Bg0, &Bs[0][l0]); gload16(Bg1, &Bs[0][l1]);
    gload16(Ag0 + GBK, &As[1][l0]); gload16(Ag1 + GBK, &As[1][l1]);
    gload16(Bg0 + GBK, &Bs[1][l0]); gload16(Bg1 + GBK, &Bs[1][l1]);

    for (int t = 0; t < GNT; ++t) {
        if (t < GNT - 1) asm volatile("s_waitcnt vmcnt(4)" ::: "memory");
        else             asm volatile("s_waitcnt vmcnt(0)" ::: "memory");
        __builtin_amdgcn_s_barrier();

        if (t + 2 < GNT) {
            const int ko = (t + 2) * GBK;
            const int nb = (t + 2) % 3;
            gload16(Ag0 + ko, &As[nb][l0]); gload16(Ag1 + ko, &As[nb][l1]);
            gload16(Bg0 + ko, &Bs[nb][l0]); gload16(Bg1 + ko, &Bs[nb][l1]);
        }

        const ushort_t* as = As[t % 3];
        const ushort_t* bs = Bs[t % 3];
        short8v a[4], b[4];
        #pragma unroll
        for (int i = 0; i < 4; ++i) a[i] = *(const short8v*)&as[aoff[i]];
        #pragma unroll
        for (int i = 0; i < 4; ++i) b[i] = *(const short8v*)&bs[boff[i]];
        #pragma unroll
        for (int i = 0; i < 4; ++i)
            #pragma unroll
            for (int j = 0; j < 4; ++j)
                acc[i][j] = __builtin_amdgcn_mfma_f32_16x16x32_bf16(a[i], b[j], acc[i][j], 0, 0, 0);
    }

    const int crow0 = bm + wm * 64 + ((lane >> 4) << 2);
    const int ccol0 = bn + wn * 64 + fr;
    if (g.Cf) {
        #pragma unroll
        for (int i = 0; i < 4; ++i)
            #pragma unroll
            for (int j = 0; j < 4; ++j)
                #pragma unroll
                for (int r = 0; r < 4; ++r)
                    g.Cf[(size_t)(crow0 + i * 16 + r) * GN + ccol0 + j * 16] = acc[i][j][r];
    } else {
        #pragma unroll
        for (int i = 0; i < 4; ++i)
            #pragma unroll
            for (int j = 0; j < 4; ++j)
                #pragma unroll
                for (int r = 0; r < 4; ++r)
                    g.C[(size_t)(crow0 + i * 16 + r) * GN + ccol0 + j * 16] = bf16_rne(acc[i][j][r]);
        if (g.vs) {   // fused V column-sum: sum bf16-rounded values (matches sparse path)
            const int bsel = (bm >= S_LEN) ? 1 : 0;
            #pragma unroll
            for (int j = 0; j < 4; ++j) {
                float part = 0.f;
                #pragma unroll
                for (int i = 0; i < 4; ++i)
                    #pragma unroll
                    for (int r = 0; r < 4; ++r)
                        part += bf16_f(bf16_rne(acc[i][j][r]));
                atomicAdd(&g.vs[bsel * D_MODEL + ccol0 + j * 16], part);
            }
        }
    }
}

// ---------------- sparse rows (pos = 1 .. 2046), 2 rows per block ----------
__global__ __launch_bounds__(768) void sparse_attn(
    const ushort_t* __restrict__ q, const ushort_t* __restrict__ k, const ushort_t* __restrict__ v,
    const float* __restrict__ vsum, const int* __restrict__ idx,
    ushort_t* __restrict__ ao) {
    const int i0 = blockIdx.x * 2;   // idx rows i0, i0+1 -> pos i0+1, i0+2
    const int b = blockIdx.y;
    const int c = threadIdx.x;       // channel 0..767 (wave == head)

    int id[2][NI];
    #pragma unroll
    for (int r = 0; r < 2; ++r)
        #pragma unroll
        for (int j = 0; j < NI; ++j) id[r][j] = idx[(i0 + r) * NI + j];
    bool dup[2][NI];
    #pragma unroll
    for (int r = 0; r < 2; ++r)
        #pragma unroll
        for (int j = 0; j < NI; ++j) {
            bool d = false;
            #pragma unroll
            for (int j2 = 0; j2 < NI; ++j2)
                if (j2 < j) d = d || (id[r][j2] == id[r][j]);
            dup[r][j] = d;
        }

    const size_t rb0 = ((size_t)(b * S_LEN + i0 + 1)) * D_MODEL + c;
    const float qv0 = bf16_f(q[rb0]);
    const float qv1 = bf16_f(q[rb0 + D_MODEL]);

    float kv[2][NI], vv[2][NI];
    #pragma unroll
    for (int r = 0; r < 2; ++r)
        #pragma unroll
        for (int j = 0; j < NI; ++j) {
            const size_t kb = ((size_t)(b * S_LEN + id[r][j])) * D_MODEL + c;
            kv[r][j] = bf16_f(k[kb]);
            vv[r][j] = bf16_f(v[kb]);
        }

    float p[2][NI];
    #pragma unroll
    for (int j = 0; j < NI; ++j) { p[0][j] = qv0 * kv[0][j]; p[1][j] = qv1 * kv[1][j]; }

    #pragma unroll
    for (int off = 32; off; off >>= 1) {
        #pragma unroll
        for (int r = 0; r < 2; ++r)
            #pragma unroll
            for (int j = 0; j < NI; ++j) p[r][j] += __shfl_xor(p[r][j], off);
    }

    const float vsc = vsum[b * D_MODEL + c];
    #pragma unroll
    for (int r = 0; r < 2; ++r) {
        float acc = vsc;
        float Z = 0.f;
        int u = 0;
        #pragma unroll
        for (int j = 0; j < NI; ++j) {
            if (dup[r][j]) continue;
            float e = expf(p[r][j] * 0.125f);
            Z += e;
            u += 1;
            acc += (e - 1.f) * vv[r][j];
        }
        Z += (float)(S_LEN - u);
        ao[rb0 + (size_t)r * D_MODEL] = bf16_rne(acc / Z);
    }
}

// ---------------- global rows: split-K partials ----------------
__global__ __launch_bounds__(256) void global_attn_part(
    const ushort_t* __restrict__ q, const ushort_t* __restrict__ k, const ushort_t* __restrict__ v,
    float* __restrict__ part) {
    const int ch = blockIdx.x;
    const int rowsel = blockIdx.y;
    const int row = rowsel ? (S_LEN - 1) : 0;
    const int hb = blockIdx.z;
    const int h = hb % NH;
    const int b = hb / NH;
    const int tid = threadIdx.x;

    __shared__ float qs[HD];
    __shared__ float ps[CHK];
    __shared__ float red[8];
    __shared__ float redv[32][72];   // padded: row stride 288B -> distinct banks

    if (tid < HD) qs[tid] = bf16_f(q[((size_t)(b * S_LEN + row)) * D_MODEL + h * HD + tid]);
    __syncthreads();

    const int t = ch * CHK + tid;
    const ushort_t* kp = &k[((size_t)(b * S_LEN + t)) * D_MODEL + h * HD];
    float s = 0.f;
    #pragma unroll
    for (int dd = 0; dd < 8; ++dd) {
        short8v kk = *(const short8v*)&kp[dd * 8];
        #pragma unroll
        for (int e = 0; e < 8; ++e)
            s += qs[dd * 8 + e] * bf16_f((unsigned short)kk[e]);
    }
    s *= 0.125f;

    float m = s;
    #pragma unroll
    for (int off = 32; off; off >>= 1) m = fmaxf(m, __shfl_xor(m, off));
    if ((tid & 63) == 0) red[tid >> 6] = m;
    __syncthreads();
    m = fmaxf(fmaxf(red[0], red[1]), fmaxf(red[2], red[3]));

    float e = expf(s - m);
    ps[tid] = e;
    float zp = e;
    #pragma unroll
    for (int off = 32; off; off >>= 1) zp += __shfl_xor(zp, off);
    if ((tid & 63) == 0) red[4 + (tid >> 6)] = zp;
    __syncthreads();
    const float E = red[4] + red[5] + red[6] + red[7];

    // vectorized PV: thread owns 8 channels, strided key groups
    const int g8 = tid >> 3;          // 0..31
    const int d8 = (tid & 7) * 8;     // 0,8,...,56
    float a8[8] = {};
    for (int tt = g8; tt < CHK; tt += 32) {
        const float wgt = ps[tt];
        short8v v8 = *(const short8v*)&v[((size_t)(b * S_LEN + ch * CHK + tt)) * D_MODEL + h * HD + d8];
        #pragma unroll
        for (int e2 = 0; e2 < 8; ++e2)
            a8[e2] += wgt * bf16_f((unsigned short)v8[e2]);
    }
    #pragma unroll
    for (int e2 = 0; e2 < 8; ++e2) redv[g8][d8 + e2] = a8[e2];
    __syncthreads();
    if (tid < HD) {
        float o = 0.f;
        #pragma unroll
        for (int gg = 0; gg < 32; ++gg) o += redv[gg][tid];
        float* pr = part + ((size_t)((hb * 2 + rowsel) * NCH + ch)) * (HD + 2);
        pr[2 + tid] = o;
        if (tid == 0) { pr[0] = m; pr[1] = E; }
    }
}

__global__ __launch_bounds__(64) void global_attn_fin(
    const float* __restrict__ part, ushort_t* __restrict__ ao) {
    const int rb = blockIdx.x;
    const int rowsel = rb & 1;
    const int hb = rb >> 1;
    const int h = hb % NH;
    const int b = hb / NH;
    const int row = rowsel ? (S_LEN - 1) : 0;
    const int d = threadIdx.x;

    const float* pr = part + (size_t)rb * NCH * (HD + 2);
    float M = -1e30f;
    #pragma unroll
    for (int c = 0; c < NCH; ++c) M = fmaxf(M, pr[c * (HD + 2)]);
    float Z = 0.f, acc = 0.f;
    #pragma unroll
    for (int c = 0; c < NCH; ++c) {
        float wgt = expf(pr[c * (HD + 2)] - M);
        Z   += pr[c * (HD + 2) + 1] * wgt;
        acc += pr[c * (HD + 2) + 2 + d] * wgt;
    }
    ao[((size_t)(b * S_LEN + row)) * D_MODEL + h * HD + d] = bf16_rne(acc / Z);
}

// ---------------- launch ----------------
extern "C" void kernel_launch(void* const* d_in, const int* in_sizes, int n_in,
                              void* d_out, int out_size, void* d_ws, size_t ws_size,
                              hipStream_t stream) {
    const float* Q  = (const float*)d_in[0];
    const float* K  = (const float*)d_in[1];
    const float* V  = (const float*)d_in[2];
    const float* Wq = (const float*)d_in[3];
    const float* Wk = (const float*)d_in[4];
    const float* Wv = (const float*)d_in[5];
    const float* Wo = (const float*)d_in[6];
    const int*  idx = (const int*)d_in[7];
    float* out = (float*)d_out;

    const size_t SZ  = (size_t)BB * S_LEN * D_MODEL;   // 3,145,728
    const size_t WSZ = (size_t)D_MODEL * D_MODEL;      // 589,824

    ushort_t* Qc  = (ushort_t*)d_ws;
    ushort_t* Kc  = Qc  + SZ;
    ushort_t* Vc  = Kc  + SZ;
    ushort_t* Wqc = Vc  + SZ;
    ushort_t* Wkc = Wqc + WSZ;
    ushort_t* Wvc = Wkc + WSZ;
    ushort_t* Woc = Wvc + WSZ;
    ushort_t* qb  = Woc + WSZ;
    ushort_t* kb  = qb  + SZ;
    ushort_t* vb  = kb  + SZ;
    ushort_t* ao  = vb  + SZ;
    float* vs   = (float*)(ao + SZ);
    float* part = vs + BB * D_MODEL;

    {   // one conversion + zero-fill dispatch
        CvtAll a{Q, K, V, Wq, Wk, Wv, Wo, Qc, Kc, Vc, Wqc, Wkc, Wvc, Woc, vs};
        cvt_all<<<dim3((unsigned)(SZ / 2048), 1, 5), 256, 0, stream>>>(a);
    }
    {   // Q,K,V projections (bf16 out); V slice also accumulates column sums
        GemmArgs g0{Qc, Wqc, qb, nullptr, nullptr};
        GemmArgs g1{Kc, Wkc, kb, nullptr, nullptr};
        GemmArgs g2{Vc, Wvc, vb, nullptr, vs};
        bf16_gemm_nt<<<dim3(D_MODEL / 128, BB * S_LEN / 128, 3), 256, 0, stream>>>(g0, g1, g2);
    }
    sparse_attn<<<dim3(S2 / 2, BB), 768, 0, stream>>>(qb, kb, vb, vs, idx, ao);
    global_attn_part<<<dim3(NCH, 2, NH * BB), 256, 0, stream>>>(qb, kb, vb, part);
    global_attn_fin<<<dim3(2 * NH * BB), 64, 0, stream>>>(part, ao);
    {   // output projection (fp32 out)
        GemmArgs g{ao, Woc, nullptr, out, nullptr};
        bf16_gemm_nt<<<dim3(D_MODEL / 128, BB * S_LEN / 128, 1), 256, 0, stream>>>(g, g, g);
    }
}